// Round 4
// baseline (726.211 us; speedup 1.0000x reference)
//
#include <hip/hip_runtime.h>
#include <hip/hip_bf16.h>

#define NTOK 8192
#define DIM 1024
#define NEXP 8
#define NT 256   // virtual K tiles: 16 segments (expert x half) x 16 tiles of BK=64
#define BK 64

typedef float f32x4 __attribute__((ext_vector_type(4)));
typedef short s16x8 __attribute__((ext_vector_type(8)));
typedef unsigned short u16;
typedef unsigned short u16x4 __attribute__((ext_vector_type(4)));

__device__ __forceinline__ u16 f2bf(float f) {
    __hip_bfloat16 h = __float2bfloat16(f);
    return *reinterpret_cast<u16*>(&h);
}

#define GLOAD16(gsrc, ldst)                                                     \
    __builtin_amdgcn_global_load_lds(                                           \
        (const __attribute__((address_space(1))) void*)(gsrc),                  \
        (__attribute__((address_space(3))) void*)(ldst), 16, 0, 0)

#define MFMA16(a, b, c) __builtin_amdgcn_mfma_f32_16x16x32_bf16((a), (b), (c), 0, 0, 0)

// ---------------- gates: softmax(z_flat @ Wg^T + bg) ----------------
__global__ __launch_bounds__(256) void gates_kernel(
    const float* __restrict__ zr, const float* __restrict__ zi,
    const float* __restrict__ Wg, const float* __restrict__ bg,
    float* __restrict__ gates)
{
    const int wave = threadIdx.x >> 6, lane = threadIdx.x & 63;
    const int n = blockIdx.x * 4 + wave;

    float v[32];
    const float* zrp = zr + (size_t)n * DIM;
    const float* zip = zi + (size_t)n * DIM;
#pragma unroll
    for (int j = 0; j < 16; ++j) v[j] = zrp[j * 64 + lane];
#pragma unroll
    for (int j = 0; j < 16; ++j) v[16 + j] = zip[j * 64 + lane];

    float s[NEXP];
#pragma unroll
    for (int e = 0; e < NEXP; ++e) {
        const float* wrow = Wg + (size_t)e * (2 * DIM);
        float a = 0.f;
#pragma unroll
        for (int j = 0; j < 32; ++j) a += v[j] * wrow[j * 64 + lane];
#pragma unroll
        for (int m = 32; m; m >>= 1) a += __shfl_xor(a, m);
        s[e] = a + bg[e];
    }
    float mx = s[0];
#pragma unroll
    for (int e = 1; e < NEXP; ++e) mx = fmaxf(mx, s[e]);
    float p[NEXP], sum = 0.f;
#pragma unroll
    for (int e = 0; e < NEXP; ++e) { p[e] = expf(s[e] - mx); sum += p[e]; }
    const float inv = 1.f / sum;
    if (lane == 0) {
#pragma unroll
        for (int e = 0; e < NEXP; ++e) gates[(size_t)n * NEXP + e] = p[e] * inv;
    }
}

// ---------------- weight fp32 -> bf16 ----------------
__global__ __launch_bounds__(256) void cvt2_kernel(
    const float* __restrict__ Wr, const float* __restrict__ Wi,
    u16* __restrict__ Wr16, u16* __restrict__ Wi16)
{
    const size_t total = (size_t)NEXP * DIM * DIM / 4;
    for (size_t i = (size_t)blockIdx.x * 256 + threadIdx.x; i < total;
         i += (size_t)gridDim.x * 256) {
        f32x4 a = ((const f32x4*)Wr)[i];
        f32x4 b = ((const f32x4*)Wi)[i];
        u16x4 pa, pb;
#pragma unroll
        for (int j = 0; j < 4; ++j) { pa[j] = f2bf(a[j]); pb[j] = f2bf(b[j]); }
        ((u16x4*)Wr16)[i] = pa;
        ((u16x4*)Wi16)[i] = pb;
    }
}

// ---------------- main MoE GEMM: 256x256 tile, 4-phase/K-tile pipeline --------
// grid (NTOK/256, DIM/256, 2), 512 threads = 8 waves (2M x 4N), per-wave 128x64.
// Virtual K = 16 segments x 1024; gate*sign folded into A-staging conversion,
// with the cvt VALU placed INSIDE the MFMA windows (ph1/ph2) for pipe overlap.
// Single vmcnt(0)+lgkmcnt(0) drain BEFORE the tile-final barrier (race-free;
// B-gloads issued ph0/ph1 get 2-3 phases of latency cover).
__global__ __launch_bounds__(512, 2) void moe_gemm4(
    const float* __restrict__ zr, const float* __restrict__ zi,
    const u16* __restrict__ Wr16, const u16* __restrict__ Wi16,
    const float* __restrict__ gates, float* __restrict__ out)
{
    extern __shared__ u16 lds[];  // [2][32768]: per buf: A[0..16383], B[16384..32767]

    const int bm = blockIdx.x, bn = blockIdx.y, sel = blockIdx.z;
    const int tid = threadIdx.x;
    const int lane = tid & 63;
    const int wid = tid >> 6;
    const int wr = wid >> 2;   // 0..1
    const int wc = wid & 3;    // 0..3

    // ---- staging addressing (validated in r3: swizzle chunk c ^= row&7,
    // inverse applied on global source) ----
    const int srow = tid >> 3;                     // 0..63
    const int schunk = (tid & 7) ^ (srow & 7);     // inverse-swizzled global chunk
    int arow[4], gidx[4], brow[4];
#pragma unroll
    for (int j = 0; j < 4; ++j) {
        const int gr = bm * 256 + srow + j * 64;
        arow[j] = gr * DIM + schunk * 8;
        gidx[j] = gr * NEXP;
        brow[j] = (bn * 256 + srow + j * 64) * DIM + schunk * 8;
    }

    // ---- fragment read addressing ----
    const int cg = lane >> 4;            // k-group 0..3
    const int l7 = lane & 7;
    const int ach0 = (cg ^ l7) * 8;      // ks=0 chunk elem offset
    const int ach1 = ((4 + cg) ^ l7) * 8;
    const int arbase = (wr * 128 + (lane & 15)) * BK;
    const int brbase = 16384 + (wc * 64 + (lane & 15)) * BK;

    f32x4 acc[8][4];
#pragma unroll
    for (int m = 0; m < 8; ++m)
#pragma unroll
        for (int n = 0; n < 4; ++n) acc[m][n] = (f32x4){0.f, 0.f, 0.f, 0.f};

    // ---- segment 0 state ----
    const float* Asrc = sel ? zi : zr;   // (half=0)^sel
    const u16* Bseg = Wr16;              // e=0, half=0
    float sg[4];
#pragma unroll
    for (int j = 0; j < 4; ++j) sg[j] = gates[gidx[j]];

    // ---- prologue: stage tile 0 into buf 0 ----
    {
        f32x4 ga[4][2];
#pragma unroll
        for (int j = 0; j < 4; ++j) {
            const float* p = Asrc + arow[j];
            ga[j][0] = *(const f32x4*)p;
            ga[j][1] = *(const f32x4*)(p + 4);
        }
#pragma unroll
        for (int i = 0; i < 4; ++i)
            GLOAD16(Bseg + brow[i], &lds[16384 + (i * 512 + tid) * 8]);
#pragma unroll
        for (int j = 0; j < 4; ++j) {
            s16x8 w;
#pragma unroll
            for (int q = 0; q < 4; ++q) {
                w[q] = (short)f2bf(ga[j][0][q] * sg[j]);
                w[4 + q] = (short)f2bf(ga[j][1][q] * sg[j]);
            }
            *(s16x8*)&lds[(tid + j * 512) * 8] = w;
        }
        asm volatile("s_waitcnt vmcnt(0) lgkmcnt(0)" ::: "memory");
        __syncthreads();
    }

    int buf = 0;
#pragma unroll 1
    for (int t = 0; t < NT; ++t) {
        const int tn = t + 1;
        if ((tn & 15) == 0) {  // segment boundary: state for tiles tn..tn+15
            const int seg = tn >> 4;
            const int e = (seg >> 1) & 7;  // seg 16 (dead staged tile): wraps, unused
            const int half = seg & 1;
            Asrc = (half ^ sel) ? zi : zr;
            Bseg = (half ? Wi16 : Wr16) + (size_t)e * DIM * DIM;
            const float sgn = (sel == 0 && half == 1) ? -1.f : 1.f;
#pragma unroll
            for (int j = 0; j < 4; ++j) sg[j] = sgn * gates[gidx[j] + e];
        }
        const int kb = (tn & 15) << 6;       // staging k base (elems)
        const int ab = (buf << 15) + arbase; // read bases for this tile
        const int bb = (buf << 15) + brbase;
        const int sb = (buf ^ 1) << 15;      // staging dest base

        // ==== ph0: issue A reg-loads + B0,B1 gloads (t+1); dsr B[ks0]+A[0..3,ks0]; MFMA
        f32x4 ga[4][2];
#pragma unroll
        for (int j = 0; j < 4; ++j) {
            const float* p = Asrc + arow[j] + kb;
            ga[j][0] = *(const f32x4*)p;
            ga[j][1] = *(const f32x4*)(p + 4);
        }
        GLOAD16(Bseg + brow[0] + kb, &lds[sb + 16384 + (0 * 512 + tid) * 8]);
        GLOAD16(Bseg + brow[1] + kb, &lds[sb + 16384 + (1 * 512 + tid) * 8]);
        s16x8 bf0[4], bf1[4], afr[4];
#pragma unroll
        for (int n = 0; n < 4; ++n) bf0[n] = *(const s16x8*)&lds[bb + n * 1024 + ach0];
#pragma unroll
        for (int m = 0; m < 4; ++m) afr[m] = *(const s16x8*)&lds[ab + m * 1024 + ach0];
        __builtin_amdgcn_s_barrier();
        __builtin_amdgcn_s_setprio(1);
#pragma unroll
        for (int m = 0; m < 4; ++m)
#pragma unroll
            for (int n = 0; n < 4; ++n) acc[m][n] = MFMA16(afr[m], bf0[n], acc[m][n]);
        __builtin_amdgcn_s_setprio(0);
        __builtin_amdgcn_s_barrier();

        // ==== ph1: dsr A[4..7,ks0]; issue B2,B3; MFMA + cvt j=0,1 inside window
#pragma unroll
        for (int m = 0; m < 4; ++m) afr[m] = *(const s16x8*)&lds[ab + (m + 4) * 1024 + ach0];
        GLOAD16(Bseg + brow[2] + kb, &lds[sb + 16384 + (2 * 512 + tid) * 8]);
        GLOAD16(Bseg + brow[3] + kb, &lds[sb + 16384 + (3 * 512 + tid) * 8]);
        __builtin_amdgcn_s_barrier();
        __builtin_amdgcn_s_setprio(1);
#pragma unroll
        for (int m = 0; m < 4; ++m)
#pragma unroll
            for (int n = 0; n < 4; ++n) acc[m + 4][n] = MFMA16(afr[m], bf0[n], acc[m + 4][n]);
#pragma unroll
        for (int j = 0; j < 2; ++j) {
            s16x8 w;
#pragma unroll
            for (int q = 0; q < 4; ++q) {
                w[q] = (short)f2bf(ga[j][0][q] * sg[j]);
                w[4 + q] = (short)f2bf(ga[j][1][q] * sg[j]);
            }
            *(s16x8*)&lds[sb + (tid + j * 512) * 8] = w;
        }
        __builtin_amdgcn_s_setprio(0);
        __builtin_amdgcn_s_barrier();

        // ==== ph2: dsr B[ks1]+A[0..3,ks1]; MFMA + cvt j=2,3 inside window
#pragma unroll
        for (int n = 0; n < 4; ++n) bf1[n] = *(const s16x8*)&lds[bb + n * 1024 + ach1];
#pragma unroll
        for (int m = 0; m < 4; ++m) afr[m] = *(const s16x8*)&lds[ab + m * 1024 + ach1];
        __builtin_amdgcn_s_barrier();
        __builtin_amdgcn_s_setprio(1);
#pragma unroll
        for (int m = 0; m < 4; ++m)
#pragma unroll
            for (int n = 0; n < 4; ++n) acc[m][n] = MFMA16(afr[m], bf1[n], acc[m][n]);
#pragma unroll
        for (int j = 2; j < 4; ++j) {
            s16x8 w;
#pragma unroll
            for (int q = 0; q < 4; ++q) {
                w[q] = (short)f2bf(ga[j][0][q] * sg[j]);
                w[4 + q] = (short)f2bf(ga[j][1][q] * sg[j]);
            }
            *(s16x8*)&lds[sb + (tid + j * 512) * 8] = w;
        }
        __builtin_amdgcn_s_setprio(0);
        __builtin_amdgcn_s_barrier();

        // ==== ph3: dsr A[4..7,ks1]; MFMA; full drain BEFORE final barrier
#pragma unroll
        for (int m = 0; m < 4; ++m) afr[m] = *(const s16x8*)&lds[ab + (m + 4) * 1024 + ach1];
        __builtin_amdgcn_s_barrier();
        __builtin_amdgcn_s_setprio(1);
#pragma unroll
        for (int m = 0; m < 4; ++m)
#pragma unroll
            for (int n = 0; n < 4; ++n) acc[m + 4][n] = MFMA16(afr[m], bf1[n], acc[m + 4][n]);
        __builtin_amdgcn_s_setprio(0);
        // drain: B-gloads for t+1 (issued ph0/ph1, 2-3 phases cover) + our ds ops,
        // so after the barrier every wave may safely read buf^1.
        asm volatile("s_waitcnt vmcnt(0) lgkmcnt(0)" ::: "memory");
        __builtin_amdgcn_s_barrier();

        buf ^= 1;
    }

    // ---- epilogue: C[row][col], col=lane&15, row=(lane>>4)*4+j (m89 layout) ----
    float* op = out + (size_t)sel * NTOK * DIM;
    const int col0 = bn * 256 + wc * 64 + (lane & 15);
    const int row0 = bm * 256 + wr * 128 + ((lane >> 4) << 2);
#pragma unroll
    for (int m = 0; m < 8; ++m)
#pragma unroll
        for (int n = 0; n < 4; ++n)
#pragma unroll
            for (int j = 0; j < 4; ++j)
                op[(size_t)(row0 + m * 16 + j) * DIM + col0 + n * 16] = acc[m][n][j];
}

extern "C" void kernel_launch(void* const* d_in, const int* in_sizes, int n_in,
                              void* d_out, int out_size, void* d_ws, size_t ws_size,
                              hipStream_t stream) {
    const float* zr = (const float*)d_in[0];
    const float* zi = (const float*)d_in[1];
    const float* Wg = (const float*)d_in[2];
    const float* bg = (const float*)d_in[3];
    const float* Wr = (const float*)d_in[4];
    const float* Wi = (const float*)d_in[5];
    float* out = (float*)d_out;

    const size_t NELEM = (size_t)NEXP * DIM * DIM;
    u16* Wr16 = (u16*)d_ws;
    u16* Wi16 = Wr16 + NELEM;
    float* gates = (float*)(Wi16 + NELEM);

    cvt2_kernel<<<2048, 256, 0, stream>>>(Wr, Wi, Wr16, Wi16);
    gates_kernel<<<NTOK / 4, 256, 0, stream>>>(zr, zi, Wg, bg, gates);

    hipFuncSetAttribute((const void*)moe_gemm4,
                        hipFuncAttributeMaxDynamicSharedMemorySize, 131072);
    dim3 grid(NTOK / 256, DIM / 256, 2);
    moe_gemm4<<<grid, 512, 131072, stream>>>(zr, zi, Wr16, Wi16, gates, out);
}

// Round 5
// 612.106 us; speedup vs baseline: 1.1864x; 1.1864x over previous
//
#include <hip/hip_runtime.h>
#include <hip/hip_bf16.h>

#define NTOK 8192
#define DIM 1024
#define NEXP 8
#define NT 256   // virtual K tiles: 16 segments (expert x half) x 16 tiles of BK=64
#define BK 64

typedef float f32x4 __attribute__((ext_vector_type(4)));
typedef short s16x8 __attribute__((ext_vector_type(8)));
typedef unsigned short u16;
typedef unsigned short u16x4 __attribute__((ext_vector_type(4)));

__device__ __forceinline__ u16 f2bf(float f) {
    __hip_bfloat16 h = __float2bfloat16(f);
    return *reinterpret_cast<u16*>(&h);
}
__device__ __forceinline__ float bf2f(u16 u) {
    unsigned v = ((unsigned)u) << 16;
    return __uint_as_float(v);
}

#define GLOAD16(gsrc, ldst)                                                     \
    __builtin_amdgcn_global_load_lds(                                           \
        (const __attribute__((address_space(1))) void*)(gsrc),                  \
        (__attribute__((address_space(3))) void*)(ldst), 16, 0, 0)

#define MFMA16(a, b, c) __builtin_amdgcn_mfma_f32_16x16x32_bf16((a), (b), (c), 0, 0, 0)

// ---------------- gates: softmax(z_flat @ Wg^T + bg) ----------------
__global__ __launch_bounds__(256) void gates_kernel(
    const float* __restrict__ zr, const float* __restrict__ zi,
    const float* __restrict__ Wg, const float* __restrict__ bg,
    float* __restrict__ gates)
{
    const int wave = threadIdx.x >> 6, lane = threadIdx.x & 63;
    const int n = blockIdx.x * 4 + wave;

    float v[32];
    const float* zrp = zr + (size_t)n * DIM;
    const float* zip = zi + (size_t)n * DIM;
#pragma unroll
    for (int j = 0; j < 16; ++j) v[j] = zrp[j * 64 + lane];
#pragma unroll
    for (int j = 0; j < 16; ++j) v[16 + j] = zip[j * 64 + lane];

    float s[NEXP];
#pragma unroll
    for (int e = 0; e < NEXP; ++e) {
        const float* wrow = Wg + (size_t)e * (2 * DIM);
        float a = 0.f;
#pragma unroll
        for (int j = 0; j < 32; ++j) a += v[j] * wrow[j * 64 + lane];
#pragma unroll
        for (int m = 32; m; m >>= 1) a += __shfl_xor(a, m);
        s[e] = a + bg[e];
    }
    float mx = s[0];
#pragma unroll
    for (int e = 1; e < NEXP; ++e) mx = fmaxf(mx, s[e]);
    float p[NEXP], sum = 0.f;
#pragma unroll
    for (int e = 0; e < NEXP; ++e) { p[e] = expf(s[e] - mx); sum += p[e]; }
    const float inv = 1.f / sum;
    if (lane == 0) {
#pragma unroll
        for (int e = 0; e < NEXP; ++e) gates[(size_t)n * NEXP + e] = p[e] * inv;
    }
}

// ---------------- fp32 -> bf16 conversion (z and W; equal element counts) ---
__global__ __launch_bounds__(256) void cvt4_kernel(
    const float* __restrict__ zr, const float* __restrict__ zi,
    const float* __restrict__ Wr, const float* __restrict__ Wi,
    u16* __restrict__ zr16, u16* __restrict__ zi16,
    u16* __restrict__ Wr16, u16* __restrict__ Wi16)
{
    const size_t total = (size_t)NEXP * DIM * DIM / 4;  // == NTOK*DIM/4
    for (size_t i = (size_t)blockIdx.x * 256 + threadIdx.x; i < total;
         i += (size_t)gridDim.x * 256) {
        f32x4 a = ((const f32x4*)zr)[i];
        f32x4 b = ((const f32x4*)zi)[i];
        f32x4 c = ((const f32x4*)Wr)[i];
        f32x4 d = ((const f32x4*)Wi)[i];
        u16x4 pa, pb, pc, pd;
#pragma unroll
        for (int j = 0; j < 4; ++j) {
            pa[j] = f2bf(a[j]); pb[j] = f2bf(b[j]);
            pc[j] = f2bf(c[j]); pd[j] = f2bf(d[j]);
        }
        ((u16x4*)zr16)[i] = pa;
        ((u16x4*)zi16)[i] = pb;
        ((u16x4*)Wr16)[i] = pc;
        ((u16x4*)Wi16)[i] = pd;
    }
}

// ---------------- main MoE GEMM: 256x256 tile, 4-phase/K-tile pipeline --------
// 512 threads = 8 waves (2M x 4N), per-wave 128x64. Virtual K = 16 seg x 1024.
// z pre-converted to bf16 (halves A-bytes); gate*sign applied in-window via
// unpack-mul-repack. XCD swizzle: one (bn,sel) group per XCD -> B stream is
// L2-shared by all 32 blocks on the XCD. All B-gloads at ph0; race-free full
// drain before tile-final barrier (cover = 4 phases).
__global__ __launch_bounds__(512, 2) void moe_gemm5(
    const u16* __restrict__ zr16, const u16* __restrict__ zi16,
    const u16* __restrict__ Wr16, const u16* __restrict__ Wi16,
    const float* __restrict__ gates, float* __restrict__ out)
{
    extern __shared__ u16 lds[];  // [2][32768]: per buf: A[0..16383], B[16384..32767]

    // XCD-aware remap: hw xcd = linear%8; give each XCD one (bn,sel) group.
    const int linear = blockIdx.x + 32 * (blockIdx.y + 4 * blockIdx.z);
    const int grp = linear & 7;
    const int bm = linear >> 3;
    const int bn = grp & 3;
    const int sel = grp >> 2;

    const int tid = threadIdx.x;
    const int lane = tid & 63;
    const int wid = tid >> 6;
    const int wr = wid >> 2;   // 0..1
    const int wc = wid & 3;    // 0..3

    // ---- staging addressing (swizzle chunk c ^= row&7, inverse on source) ----
    const int srow = tid >> 3;
    const int schunk = (tid & 7) ^ (srow & 7);
    int arow[4], gidx[4], brow[4];
#pragma unroll
    for (int j = 0; j < 4; ++j) {
        const int gr = bm * 256 + srow + j * 64;
        arow[j] = gr * DIM + schunk * 8;
        gidx[j] = gr * NEXP;
        brow[j] = (bn * 256 + srow + j * 64) * DIM + schunk * 8;
    }

    // ---- fragment read addressing ----
    const int cg = lane >> 4;
    const int l7 = lane & 7;
    const int ach0 = (cg ^ l7) * 8;
    const int ach1 = ((4 + cg) ^ l7) * 8;
    const int arbase = (wr * 128 + (lane & 15)) * BK;
    const int brbase = 16384 + (wc * 64 + (lane & 15)) * BK;

    f32x4 acc[8][4];
#pragma unroll
    for (int m = 0; m < 8; ++m)
#pragma unroll
        for (int n = 0; n < 4; ++n) acc[m][n] = (f32x4){0.f, 0.f, 0.f, 0.f};

    // ---- segment 0 state ----
    const u16* Asrc = sel ? zi16 : zr16;   // (half=0)^sel
    const u16* Bseg = Wr16;                // e=0, half=0
    float sg[4];
#pragma unroll
    for (int j = 0; j < 4; ++j) sg[j] = gates[gidx[j]];

    // ---- prologue: stage tile 0 into buf 0 ----
    {
        s16x8 ga[4];
#pragma unroll
        for (int j = 0; j < 4; ++j) ga[j] = *(const s16x8*)(Asrc + arow[j]);
#pragma unroll
        for (int i = 0; i < 4; ++i)
            GLOAD16(Bseg + brow[i], &lds[16384 + (i * 512 + tid) * 8]);
#pragma unroll
        for (int j = 0; j < 4; ++j) {
            s16x8 w;
#pragma unroll
            for (int q = 0; q < 8; ++q)
                w[q] = (short)f2bf(bf2f((u16)ga[j][q]) * sg[j]);
            *(s16x8*)&lds[(tid + j * 512) * 8] = w;
        }
        asm volatile("s_waitcnt vmcnt(0) lgkmcnt(0)" ::: "memory");
        __syncthreads();
    }

    int buf = 0;
#pragma unroll 1
    for (int t = 0; t < NT; ++t) {
        const int tn = t + 1;
        if ((tn & 15) == 0) {  // segment boundary: state for tiles tn..tn+15
            const int seg = tn >> 4;
            const int e = (seg >> 1) & 7;  // seg 16 (dead staged tile) wraps, unused
            const int half = seg & 1;
            Asrc = (half ^ sel) ? zi16 : zr16;
            Bseg = (half ? Wi16 : Wr16) + (size_t)e * DIM * DIM;
            const float sgn = (sel == 0 && half == 1) ? -1.f : 1.f;
#pragma unroll
            for (int j = 0; j < 4; ++j) sg[j] = sgn * gates[gidx[j] + e];
        }
        const int kb = (tn & 15) << 6;       // staging k base (elems)
        const int ab = (buf << 15) + arbase;
        const int bb = (buf << 15) + brbase;
        const int sb = (buf ^ 1) << 15;      // staging dest base

        // ==== ph0: issue ALL t+1 loads (A reg + B0..B3 glds); dsr B[ks0]+A[0..3,ks0]; MFMA
        s16x8 ga[4];
#pragma unroll
        for (int j = 0; j < 4; ++j) ga[j] = *(const s16x8*)(Asrc + arow[j] + kb);
        GLOAD16(Bseg + brow[0] + kb, &lds[sb + 16384 + (0 * 512 + tid) * 8]);
        GLOAD16(Bseg + brow[1] + kb, &lds[sb + 16384 + (1 * 512 + tid) * 8]);
        GLOAD16(Bseg + brow[2] + kb, &lds[sb + 16384 + (2 * 512 + tid) * 8]);
        GLOAD16(Bseg + brow[3] + kb, &lds[sb + 16384 + (3 * 512 + tid) * 8]);
        s16x8 bf0[4], bf1[4], afr[4];
#pragma unroll
        for (int n = 0; n < 4; ++n) bf0[n] = *(const s16x8*)&lds[bb + n * 1024 + ach0];
#pragma unroll
        for (int m = 0; m < 4; ++m) afr[m] = *(const s16x8*)&lds[ab + m * 1024 + ach0];
        __builtin_amdgcn_s_barrier();
        __builtin_amdgcn_s_setprio(1);
#pragma unroll
        for (int m = 0; m < 4; ++m)
#pragma unroll
            for (int n = 0; n < 4; ++n) acc[m][n] = MFMA16(afr[m], bf0[n], acc[m][n]);
        __builtin_amdgcn_s_setprio(0);
        __builtin_amdgcn_s_barrier();

        // ==== ph1: dsr A[4..7,ks0]; MFMA + cvt j=0,1 inside window
#pragma unroll
        for (int m = 0; m < 4; ++m) afr[m] = *(const s16x8*)&lds[ab + (m + 4) * 1024 + ach0];
        __builtin_amdgcn_s_barrier();
        __builtin_amdgcn_s_setprio(1);
#pragma unroll
        for (int m = 0; m < 4; ++m)
#pragma unroll
            for (int n = 0; n < 4; ++n) acc[m + 4][n] = MFMA16(afr[m], bf0[n], acc[m + 4][n]);
#pragma unroll
        for (int j = 0; j < 2; ++j) {
            s16x8 w;
#pragma unroll
            for (int q = 0; q < 8; ++q)
                w[q] = (short)f2bf(bf2f((u16)ga[j][q]) * sg[j]);
            *(s16x8*)&lds[sb + (tid + j * 512) * 8] = w;
        }
        __builtin_amdgcn_s_setprio(0);
        __builtin_amdgcn_s_barrier();

        // ==== ph2: dsr B[ks1]+A[0..3,ks1]; MFMA + cvt j=2,3 inside window
#pragma unroll
        for (int n = 0; n < 4; ++n) bf1[n] = *(const s16x8*)&lds[bb + n * 1024 + ach1];
#pragma unroll
        for (int m = 0; m < 4; ++m) afr[m] = *(const s16x8*)&lds[ab + m * 1024 + ach1];
        __builtin_amdgcn_s_barrier();
        __builtin_amdgcn_s_setprio(1);
#pragma unroll
        for (int m = 0; m < 4; ++m)
#pragma unroll
            for (int n = 0; n < 4; ++n) acc[m][n] = MFMA16(afr[m], bf1[n], acc[m][n]);
#pragma unroll
        for (int j = 2; j < 4; ++j) {
            s16x8 w;
#pragma unroll
            for (int q = 0; q < 8; ++q)
                w[q] = (short)f2bf(bf2f((u16)ga[j][q]) * sg[j]);
            *(s16x8*)&lds[sb + (tid + j * 512) * 8] = w;
        }
        __builtin_amdgcn_s_setprio(0);
        __builtin_amdgcn_s_barrier();

        // ==== ph3: dsr A[4..7,ks1]; MFMA; full drain BEFORE final barrier
#pragma unroll
        for (int m = 0; m < 4; ++m) afr[m] = *(const s16x8*)&lds[ab + (m + 4) * 1024 + ach1];
        __builtin_amdgcn_s_barrier();
        __builtin_amdgcn_s_setprio(1);
#pragma unroll
        for (int m = 0; m < 4; ++m)
#pragma unroll
            for (int n = 0; n < 4; ++n) acc[m + 4][n] = MFMA16(afr[m], bf1[n], acc[m + 4][n]);
        __builtin_amdgcn_s_setprio(0);
        asm volatile("s_waitcnt vmcnt(0) lgkmcnt(0)" ::: "memory");
        __builtin_amdgcn_s_barrier();

        buf ^= 1;
    }

    // ---- epilogue: C[row][col], col=lane&15, row=(lane>>4)*4+j (m89 layout) ----
    float* op = out + (size_t)sel * NTOK * DIM;
    const int col0 = bn * 256 + wc * 64 + (lane & 15);
    const int row0 = bm * 256 + wr * 128 + ((lane >> 4) << 2);
#pragma unroll
    for (int m = 0; m < 8; ++m)
#pragma unroll
        for (int n = 0; n < 4; ++n)
#pragma unroll
            for (int j = 0; j < 4; ++j)
                op[(size_t)(row0 + m * 16 + j) * DIM + col0 + n * 16] = acc[m][n][j];
}

extern "C" void kernel_launch(void* const* d_in, const int* in_sizes, int n_in,
                              void* d_out, int out_size, void* d_ws, size_t ws_size,
                              hipStream_t stream) {
    const float* zr = (const float*)d_in[0];
    const float* zi = (const float*)d_in[1];
    const float* Wg = (const float*)d_in[2];
    const float* bg = (const float*)d_in[3];
    const float* Wr = (const float*)d_in[4];
    const float* Wi = (const float*)d_in[5];
    float* out = (float*)d_out;

    const size_t NELEM = (size_t)NEXP * DIM * DIM;  // == NTOK*DIM
    u16* zr16 = (u16*)d_ws;
    u16* zi16 = zr16 + NELEM;
    u16* Wr16 = zi16 + NELEM;
    u16* Wi16 = Wr16 + NELEM;
    float* gates = (float*)(Wi16 + NELEM);

    cvt4_kernel<<<2048, 256, 0, stream>>>(zr, zi, Wr, Wi, zr16, zi16, Wr16, Wi16);
    gates_kernel<<<NTOK / 4, 256, 0, stream>>>(zr, zi, Wg, bg, gates);

    hipFuncSetAttribute((const void*)moe_gemm5,
                        hipFuncAttributeMaxDynamicSharedMemorySize, 131072);
    dim3 grid(NTOK / 256, DIM / 256, 2);
    moe_gemm5<<<grid, 512, 131072, stream>>>(zr16, zi16, Wr16, Wi16, gates, out);
}